// Round 4
// baseline (356.912 us; speedup 1.0000x reference)
//
#include <hip/hip_runtime.h>
#include <math.h>

// CapsuleLayer dynamic routing, MI355X.
// B=4096, L=200, Din=Dout=64, K=8, 3 iterations.
//
// Key identity: low_new = lc @ S never needs materializing.
//   high_pre = W @ (lc@S) = (W@lc) @ S             (hp then tiny projection)
//   delta    = high @ (lc@S)^T = (high@S^T) @ lc^T (hs then row dots)
// Only big array touched is lc (210 MB, fits 256 MB L3).
//
// Step-2 is chunk-parallel: the 8 thread-groups partition L (not k), so each
// lc row is read ONCE per block (was 8x). Per-chunk hp partials go to an LDS
// buffer that OVERLAYS the S tile (S staged after the reduce), keeping LDS at
// ~29.5 KB -> 5 blocks/CU.
//
// ws layout (floats):
//   Bc      [K*L]   = 1,600      partial [B*K*L] = 6,553,600
// partial2 [16*K*L] lives in d_out (fully overwritten by the final pass).

#define B_SZ  4096
#define L_SZ  200
#define DINK  64
#define DOUTK 64
#define K_SZ  8

// ---------------------------------------------------------------- init Bc
__global__ __launch_bounds__(256) void k_init(const float* __restrict__ Bm,
                                              float* __restrict__ Bc) {
    int i = blockIdx.x * 256 + threadIdx.x;
    if (i < K_SZ * L_SZ) Bc[i] = Bm[i];
}

// ------------------------------------------- one routing iteration (fused)
// grid 4096 (one block per batch) x 256 threads.
// WRITE_OUT=0: compute delta partial. WRITE_OUT=1: write final high.
template<int WRITE_OUT>
__global__ __launch_bounds__(256) void k_route(const float* __restrict__ lc_g,
                                               const int* __restrict__ seq_len,
                                               const float* __restrict__ S_g,
                                               const float* __restrict__ Bc,
                                               float* __restrict__ partial,
                                               float* __restrict__ out) {
    __shared__ float W_s[K_SZ][L_SZ];      // 6.4 KB  unnormalized exp(B-m)
    __shared__ float ovl[64 * 65];         // 16.6 KB overlay:
                                           //   phase A: hp_part[8][8][64] (16 KB)
                                           //   phase B: Ss[64][65] (padded S)
    __shared__ float hp_s[K_SZ][DINK];     // 2 KB
    __shared__ float hx_s[K_SZ][DOUTK];    // 2 KB
    __shared__ float hs_s[K_SZ][DINK];     // 2 KB
    float (*hp_part)[K_SZ][DINK] = (float (*)[K_SZ][DINK])ovl;
    float (*Ss)[65] = (float (*)[65])ovl;

    int t = threadIdx.x;
    int b = blockIdx.x;
    long lbase = (long)b * (L_SZ * DINK);
    const float2* lc2 = (const float2*)(lc_g + lbase);
    int sl = seq_len[b];
    int k = t >> 5, g = t & 31;            // k doubles as chunk index c in step 2

    // 1. masked softmax stats over L for row k (32 lanes per k)
    const float* bk = Bc + k * L_SZ;
    float m = -3.4e38f;
    for (int l = g; l < sl; l += 32) m = fmaxf(m, bk[l]);
    #pragma unroll
    for (int s = 16; s > 0; s >>= 1) m = fmaxf(m, __shfl_xor(m, s, 32));
    float sum = 0.f;
    for (int l = g; l < sl; l += 32) {
        float e = __expf(bk[l] - m);
        sum += e;
        W_s[k][l] = e;                      // normalization folded into step 3
    }
    #pragma unroll
    for (int s = 16; s > 0; s >>= 1) sum += __shfl_xor(sum, s, 32);
    float rinv = 1.0f / sum;                // lives in (k,g) thread; reused step 3
    __syncthreads();

    // 2. chunk-parallel hp partials: group c owns rows l = 32j + 4c .. +3.
    //    Each lc row is read ONCE per block; 16 FMA per 8B load.
    {
        float2 acc[K_SZ];
        #pragma unroll
        for (int kk = 0; kk < K_SZ; ++kk) acc[kk] = make_float2(0.f, 0.f);
        int c = k;
        for (int j = 0;; ++j) {
            int l = 32 * j + 4 * c;
            if (l >= sl) break;
            if (l + 4 <= sl) {              // full quad: b128 W broadcast
                float2 v0 = lc2[(l + 0) * 32 + g];
                float2 v1 = lc2[(l + 1) * 32 + g];
                float2 v2 = lc2[(l + 2) * 32 + g];
                float2 v3 = lc2[(l + 3) * 32 + g];
                #pragma unroll
                for (int kk = 0; kk < K_SZ; ++kk) {
                    float4 w = *(const float4*)&W_s[kk][l];   // 16B-aligned
                    acc[kk].x += w.x * v0.x + w.y * v1.x + w.z * v2.x + w.w * v3.x;
                    acc[kk].y += w.x * v0.y + w.y * v1.y + w.z * v2.y + w.w * v3.y;
                }
            } else {                        // tail (< 4 rows before sl)
                for (int u = l; u < sl; ++u) {
                    float2 v = lc2[u * 32 + g];
                    #pragma unroll
                    for (int kk = 0; kk < K_SZ; ++kk) {
                        float w = W_s[kk][u];
                        acc[kk].x += w * v.x; acc[kk].y += w * v.y;
                    }
                }
            }
        }
        #pragma unroll
        for (int kk = 0; kk < K_SZ; ++kk)
            *(float2*)&hp_part[c][kk][2 * g] = acc[kk];   // zero if chunk empty
    }
    __syncthreads();

    // 3. reduce hp over the 8 chunks; fold in rinv (thread (k,g) owns cols 2g,2g+1)
    {
        float2 r = make_float2(0.f, 0.f);
        #pragma unroll
        for (int c = 0; c < K_SZ; ++c) {
            float2 p = *(const float2*)&hp_part[c][k][2 * g];
            r.x += p.x; r.y += p.y;
        }
        r.x *= rinv; r.y *= rinv;
        *(float2*)&hp_s[k][2 * g] = r;
    }
    __syncthreads();                        // hp_part dead from here

    // 4. stage S into the overlay (L2-hot; padded rows, <=2-way banks)
    {
        const float4* S4 = (const float4*)S_g;
        for (int j = t; j < 1024; j += 256) {
            float4 v = S4[j];
            int r = j >> 4, cc = (j & 15) * 4;
            Ss[r][cc] = v.x; Ss[r][cc+1] = v.y; Ss[r][cc+2] = v.z; Ss[r][cc+3] = v.w;
        }
    }
    __syncthreads();

    // 5. high[k][o] = sum_i hp[k][i]*S[i][o]; squash.  thread: (k, o=2g,2g+1)
    {
        float h0 = 0.f, h1 = 0.f;
        #pragma unroll 8
        for (int i = 0; i < DINK; ++i) {
            float p = hp_s[k][i];                         // broadcast
            float2 sv = *(const float2*)&Ss[i][2 * g];    // b64, 2-way banks
            h0 += p * sv.x; h1 += p * sv.y;
        }
        float nn = h0 * h0 + h1 * h1;
        #pragma unroll
        for (int s = 16; s > 0; s >>= 1) nn += __shfl_xor(nn, s, 32);
        float sc = nn / ((1.0f + nn) * sqrtf(nn + 1e-9f));
        h0 *= sc; h1 *= sc;
        if (WRITE_OUT) {
            float2* ob2 = (float2*)(out + (long)b * (K_SZ * DOUTK) + k * DOUTK);
            ob2[g] = make_float2(h0, h1);
            return;
        }
        *(float2*)&hx_s[k][2 * g] = make_float2(h0, h1);
    }
    __syncthreads();

    // 6. hs[k][i] = sum_o high[k][o]*S[i][o]   thread: (k, i=2g,2g+1)
    {
        float s0 = 0.f, s1 = 0.f;
        int i0 = 2 * g, i1 = 2 * g + 1;
        #pragma unroll 8
        for (int o = 0; o < DOUTK; ++o) {
            float hv = hx_s[k][o];          // broadcast
            s0 += hv * Ss[i0][o];           // 2-way banks
            s1 += hv * Ss[i1][o];
        }
        *(float2*)&hs_s[k][2 * g] = make_float2(s0, s1);
    }
    __syncthreads();

    // 7. delta partial[k][l] = sum_i hs[k][i]*lc[l][i]  (ALL l, unmasked)
    if (t < L_SZ) {
        const float4* row4 = (const float4*)(lc_g + lbase + (long)t * DINK);
        float* pb = partial + (long)b * (K_SZ * L_SZ);
        float acc[K_SZ] = {};
        #pragma unroll
        for (int i4 = 0; i4 < 16; ++i4) {
            float4 v = row4[i4];            // L1/L2-hot from step 2
            #pragma unroll
            for (int kk = 0; kk < K_SZ; ++kk) {
                float4 h = *(const float4*)&hs_s[kk][i4 * 4];  // b128 broadcast
                acc[kk] += v.x * h.x + v.y * h.y + v.z * h.z + v.w * h.w;
            }
        }
        #pragma unroll
        for (int kk = 0; kk < K_SZ; ++kk)
            pb[kk * L_SZ + t] = acc[kk];    // coalesced over t
    }
}

// --------------------------- deterministic two-stage reduce of partials
// Stage A: grid 800 = 50 col-groups x 16 batch-chunks; coalesced 128B reads.
__global__ __launch_bounds__(256) void k_reduceA(const float* __restrict__ partial,
                                                 float* __restrict__ partial2) {
    __shared__ float red[256];
    int x = blockIdx.x % 50;       // 32-output group
    int y = blockIdx.x / 50;       // 256-batch chunk
    int t = threadIdx.x;
    int i = x * 32 + (t & 31);
    int sub = t >> 5;
    float s = 0.f;
    for (int p = y * 256 + sub; p < (y + 1) * 256; p += 8)
        s += partial[(long)p * (K_SZ * L_SZ) + i];
    red[t] = s;
    __syncthreads();
    for (int step = 4; step >= 1; step >>= 1) {
        if (sub < step) red[t] += red[t + step * 32];
        __syncthreads();
    }
    if (sub == 0) partial2[y * (K_SZ * L_SZ) + i] = red[t];
}

// Stage B: fold 16 chunk-partials into Bc. grid 7 x 256.
__global__ __launch_bounds__(256) void k_reduceB(const float* __restrict__ partial2,
                                                 float* __restrict__ Bc) {
    int i = blockIdx.x * 256 + threadIdx.x;
    if (i < K_SZ * L_SZ) {
        float s = 0.f;
        #pragma unroll
        for (int y = 0; y < 16; ++y) s += partial2[y * (K_SZ * L_SZ) + i];
        Bc[i] += s;
    }
}

extern "C" void kernel_launch(void* const* d_in, const int* in_sizes, int n_in,
                              void* d_out, int out_size, void* d_ws, size_t ws_size,
                              hipStream_t stream) {
    const float* lc = (const float*)d_in[0];   // [4096,200,64]
    const int*   sl = (const int*)d_in[1];     // [4096,1]
    const float* Bm = (const float*)d_in[2];   // [1,8,200]
    const float* S  = (const float*)d_in[3];   // [64,64]
    float* out = (float*)d_out;                // [4096,8,64]
    float* ws  = (float*)d_ws;

    float* Bc      = ws;                       // 1,600 floats
    float* partial = ws + 1600;                // 6,553,600 floats
    float* p2      = out;                      // scratch: overwritten by final pass

    k_init<<<7, 256, 0, stream>>>(Bm, Bc);

    k_route<0><<<B_SZ, 256, 0, stream>>>(lc, sl, S, Bc, partial, out);
    k_reduceA <<<800, 256, 0, stream>>>(partial, p2);
    k_reduceB <<<7, 256, 0, stream>>>(p2, Bc);
    k_route<0><<<B_SZ, 256, 0, stream>>>(lc, sl, S, Bc, partial, out);
    k_reduceA <<<800, 256, 0, stream>>>(partial, p2);
    k_reduceB <<<7, 256, 0, stream>>>(p2, Bc);
    k_route<1><<<B_SZ, 256, 0, stream>>>(lc, sl, S, Bc, partial, out);
}

// Round 5
// 287.395 us; speedup vs baseline: 1.2419x; 1.2419x over previous
//
#include <hip/hip_runtime.h>
#include <math.h>

// CapsuleLayer dynamic routing, MI355X.
// B=4096, L=200, Din=Dout=64, K=8, 3 iterations.
//
// Key identity: low_new = lc @ S never needs materializing.
//   high_pre = W @ (lc@S) = (W@lc) @ S             (hp then tiny projection)
//   delta    = high @ (lc@S)^T = (high@S^T) @ lc^T (hs then row dots)
// Only big array touched is lc (210 MB, fits 256 MB L3).
//
// Occupancy is the lever (R2-R4 were all latency-bound at <=47% occ):
// S/St read from global (L1-hot, coalesced; St = S^T precomputed in k_init),
// hp_part shrunk to 4 wave-chunks (8 KB) and overlaid by hx/hs after its
// last read.  LDS = 16.6 KB -> 8 blocks/CU = 32 waves (100% cap).
//
// ws layout (floats): Bc[1600] | St[4096] | partial[B*K*L = 6,553,600]
// partial2 [16*K*L] lives in d_out (fully overwritten by the final pass).

#define B_SZ  4096
#define L_SZ  200
#define DINK  64
#define DOUTK 64
#define K_SZ  8

// ---------------------------- init: copy Bc + transpose S into St
__global__ __launch_bounds__(256) void k_init(const float* __restrict__ Bm,
                                              const float* __restrict__ S,
                                              float* __restrict__ Bc,
                                              float* __restrict__ St) {
    int i = blockIdx.x * 256 + threadIdx.x;
    if (i < K_SZ * L_SZ) Bc[i] = Bm[i];
    int j = i - K_SZ * L_SZ;
    if (j >= 0 && j < DINK * DOUTK) {
        int o = j >> 6, ii = j & 63;
        St[j] = S[ii * DOUTK + o];     // St[o][i] = S[i][o]
    }
}

// ------------------------------------------- one routing iteration (fused)
// grid 4096 (one block per batch) x 256 threads.
// WRITE_OUT=0: compute delta partial. WRITE_OUT=1: write final high.
template<int WRITE_OUT>
__global__ __launch_bounds__(256) void k_route(const float* __restrict__ lc_g,
                                               const int* __restrict__ seq_len,
                                               const float* __restrict__ S_g,
                                               const float* __restrict__ St_g,
                                               const float* __restrict__ Bc,
                                               float* __restrict__ partial,
                                               float* __restrict__ out) {
    __shared__ float W_s[K_SZ][L_SZ];      // 6.4 KB  unnormalized exp(B-m)
    __shared__ float hp_s[K_SZ][DINK];     // 2 KB    W@lc normalized
    __shared__ float ovl[4 * K_SZ * DINK]; // 8 KB:  phase A hp_part[4][8][64]
                                           //        phase B hx[8][64] | hs[8][64]
    float (*hp_part)[K_SZ][DINK] = (float (*)[K_SZ][DINK])ovl;
    float (*hx_s)[DINK] = (float (*)[DINK])(ovl);
    float (*hs_s)[DINK] = (float (*)[DINK])(ovl + K_SZ * DINK);

    int t = threadIdx.x;
    int b = blockIdx.x;
    long lbase = (long)b * (L_SZ * DINK);
    const float* lcb = lc_g + lbase;
    int sl = seq_len[b];
    int k = t >> 5, g = t & 31;            // group mapping (softmax & tiny mats)
    int w = t >> 6, c = t & 63;            // wave mapping (step 2)

    // 1. masked softmax stats over L for row k (32 lanes per k)
    const float* bk = Bc + k * L_SZ;
    float m = -3.4e38f;
    for (int l = g; l < sl; l += 32) m = fmaxf(m, bk[l]);
    #pragma unroll
    for (int s = 16; s; s >>= 1) m = fmaxf(m, __shfl_xor(m, s, 32));
    float sum = 0.f;
    for (int l = g; l < sl; l += 32) {
        float e = __expf(bk[l] - m);
        sum += e;
        W_s[k][l] = e;                      // normalization folded into step 3
    }
    #pragma unroll
    for (int s = 16; s; s >>= 1) sum += __shfl_xor(sum, s, 32);
    float rinv = 1.0f / sum;                // thread (k,g) reuses this in step 3
    __syncthreads();                        // B1

    // 2. wave-chunk hp partials: wave w owns quads l = 16j + 4w; lane owns col c.
    //    Each lc row read ONCE per block, 256B coalesced per wave.
    {
        float acc[K_SZ];
        #pragma unroll
        for (int kk = 0; kk < K_SZ; ++kk) acc[kk] = 0.f;
        for (int l = 4 * w; l < sl; l += 16) {
            if (l + 4 <= sl) {
                float v0 = lcb[(l + 0) * DINK + c];
                float v1 = lcb[(l + 1) * DINK + c];
                float v2 = lcb[(l + 2) * DINK + c];
                float v3 = lcb[(l + 3) * DINK + c];
                #pragma unroll
                for (int kk = 0; kk < K_SZ; ++kk) {
                    float4 w4 = *(const float4*)&W_s[kk][l];   // rows 16B-aligned
                    acc[kk] += w4.x * v0 + w4.y * v1 + w4.z * v2 + w4.w * v3;
                }
            } else {
                for (int u = l; u < sl; ++u) {
                    float v = lcb[u * DINK + c];
                    #pragma unroll
                    for (int kk = 0; kk < K_SZ; ++kk) acc[kk] += W_s[kk][u] * v;
                }
            }
        }
        #pragma unroll
        for (int kk = 0; kk < K_SZ; ++kk) hp_part[w][kk][c] = acc[kk];
    }
    __syncthreads();                        // B2

    // 3. reduce hp over the 4 wave-chunks; fold in rinv
    {
        float2 r = make_float2(0.f, 0.f);
        #pragma unroll
        for (int cc = 0; cc < 4; ++cc) {
            float2 p = *(const float2*)&hp_part[cc][k][2 * g];
            r.x += p.x; r.y += p.y;
        }
        *(float2*)&hp_s[k][2 * g] = make_float2(r.x * rinv, r.y * rinv);
    }
    __syncthreads();                        // B3 (also overlay anti-hazard)

    // 4. high[k][o] = sum_i hp[k][i]*S[i][o]; squash. o=2g,2g+1; S coalesced.
    {
        float h0 = 0.f, h1 = 0.f;
        const float* sp = S_g + 2 * g;
        #pragma unroll 8
        for (int i = 0; i < DINK; ++i) {
            float p = hp_s[k][i];                        // LDS broadcast (same wave wrote it)
            float2 sv = *(const float2*)(sp + i * DOUTK); // L1-hot, coalesced
            h0 += p * sv.x; h1 += p * sv.y;
        }
        float nn = h0 * h0 + h1 * h1;
        #pragma unroll
        for (int s = 16; s; s >>= 1) nn += __shfl_xor(nn, s, 32);
        float sc = nn / ((1.0f + nn) * sqrtf(nn + 1e-9f));
        h0 *= sc; h1 *= sc;
        if (WRITE_OUT) {
            float2* ob2 = (float2*)(out + (long)b * (K_SZ * DOUTK) + k * DOUTK);
            ob2[g] = make_float2(h0, h1);
            return;
        }
        *(float2*)&hx_s[k][2 * g] = make_float2(h0, h1);
        // consumer of hx_s[k][*] is this same wave -> no barrier needed
    }

    // 5. hs[k][i] = sum_o high[k][o]*S[i][o] via St (transposed): coalesced.
    {
        float s0 = 0.f, s1 = 0.f;
        const float* stp = St_g + 2 * g;
        #pragma unroll 8
        for (int o = 0; o < DOUTK; ++o) {
            float hv = hx_s[k][o];                        // LDS broadcast, same wave
            float2 sv = *(const float2*)(stp + o * DINK); // L1-hot, coalesced
            s0 += hv * sv.x; s1 += hv * sv.y;
        }
        *(float2*)&hs_s[k][2 * g] = make_float2(s0, s1);
    }
    __syncthreads();                        // B4: hs read cross-wave below

    // 6. delta partial[k][l] = sum_i hs[k][i]*lc[l][i]  (ALL l, unmasked)
    if (t < L_SZ) {
        const float4* row4 = (const float4*)(lcb + (long)t * DINK);
        float* pb = partial + (long)b * (K_SZ * L_SZ);
        float acc[K_SZ] = {};
        #pragma unroll
        for (int i4 = 0; i4 < 16; ++i4) {
            float4 v = row4[i4];            // L1/L2-hot from step 2
            #pragma unroll
            for (int kk = 0; kk < K_SZ; ++kk) {
                float4 h = *(const float4*)&hs_s[kk][i4 * 4];  // b128 broadcast
                acc[kk] += v.x * h.x + v.y * h.y + v.z * h.z + v.w * h.w;
            }
        }
        #pragma unroll
        for (int kk = 0; kk < K_SZ; ++kk)
            pb[kk * L_SZ + t] = acc[kk];    // coalesced over t
    }
}

// --------------------------- deterministic two-stage reduce of partials
// Stage A: grid 800 = 50 col-groups x 16 batch-chunks; coalesced 128B reads.
__global__ __launch_bounds__(256) void k_reduceA(const float* __restrict__ partial,
                                                 float* __restrict__ partial2) {
    __shared__ float red[256];
    int x = blockIdx.x % 50;       // 32-output group
    int y = blockIdx.x / 50;       // 256-batch chunk
    int t = threadIdx.x;
    int i = x * 32 + (t & 31);
    int sub = t >> 5;
    float s = 0.f;
    for (int p = y * 256 + sub; p < (y + 1) * 256; p += 8)
        s += partial[(long)p * (K_SZ * L_SZ) + i];
    red[t] = s;
    __syncthreads();
    for (int step = 4; step >= 1; step >>= 1) {
        if (sub < step) red[t] += red[t + step * 32];
        __syncthreads();
    }
    if (sub == 0) partial2[y * (K_SZ * L_SZ) + i] = red[t];
}

// Stage B: fold 16 chunk-partials into Bc. grid 7 x 256.
__global__ __launch_bounds__(256) void k_reduceB(const float* __restrict__ partial2,
                                                 float* __restrict__ Bc) {
    int i = blockIdx.x * 256 + threadIdx.x;
    if (i < K_SZ * L_SZ) {
        float s = 0.f;
        #pragma unroll
        for (int y = 0; y < 16; ++y) s += partial2[y * (K_SZ * L_SZ) + i];
        Bc[i] += s;
    }
}

extern "C" void kernel_launch(void* const* d_in, const int* in_sizes, int n_in,
                              void* d_out, int out_size, void* d_ws, size_t ws_size,
                              hipStream_t stream) {
    const float* lc = (const float*)d_in[0];   // [4096,200,64]
    const int*   sl = (const int*)d_in[1];     // [4096,1]
    const float* Bm = (const float*)d_in[2];   // [1,8,200]
    const float* S  = (const float*)d_in[3];   // [64,64]
    float* out = (float*)d_out;                // [4096,8,64]
    float* ws  = (float*)d_ws;

    float* Bc      = ws;                       // 1,600 floats
    float* St      = ws + 1600;                // 4,096 floats (S transposed)
    float* partial = St + 4096;                // 6,553,600 floats
    float* p2      = out;                      // scratch: overwritten by final pass

    k_init<<<23, 256, 0, stream>>>(Bm, S, Bc, St);

    k_route<0><<<B_SZ, 256, 0, stream>>>(lc, sl, S, St, Bc, partial, out);
    k_reduceA <<<800, 256, 0, stream>>>(partial, p2);
    k_reduceB <<<7, 256, 0, stream>>>(p2, Bc);
    k_route<0><<<B_SZ, 256, 0, stream>>>(lc, sl, S, St, Bc, partial, out);
    k_reduceA <<<800, 256, 0, stream>>>(partial, p2);
    k_reduceB <<<7, 256, 0, stream>>>(p2, Bc);
    k_route<1><<<B_SZ, 256, 0, stream>>>(lc, sl, S, St, Bc, partial, out);
}